// Round 19
// baseline (1792.705 us; speedup 1.0000x reference)
//
#include <hip/hip_runtime.h>

#define T_STEPS 2048
#define TOTAL   2064   // T_STEPS + 16 (deepest lag: TT), multiple of 8

typedef _Float16 h2 __attribute__((ext_vector_type(2)));
typedef _Float16 h8 __attribute__((ext_vector_type(8)));
typedef float    f4v __attribute__((ext_vector_type(4)));

__device__ __forceinline__ float fast_rcp(float x) { return __builtin_amdgcn_rcpf(x); }
__device__ __forceinline__ float sig_f(float x) { return fast_rcp(1.0f + __expf(-x)); }
__device__ __forceinline__ float tanh_f(float x) {
    float e = __expf(-2.0f * x);
    return fmaf(2.0f, fast_rcp(1.0f + e), -1.0f);
}
__device__ __forceinline__ float gate_act(float x, float zm, float sm, float sa) {
    float e = __expf(-x * zm);
    return fmaf(fast_rcp(1.0f + e), sm, sa);
}

#if __has_builtin(__builtin_amdgcn_fdot2)
#define FDOT2(a, b, c) __builtin_amdgcn_fdot2((a), (b), (c), false)
#else
__device__ __forceinline__ float FDOT2(h2 a, h2 b, float c) {
    return fmaf((float)a.x, (float)b.x, fmaf((float)a.y, (float)b.y, c));
}
#endif

// Drain ONLY lgkmcnt (LDS) before barrier — never vmcnt (R7 win).
#define LDS_BARRIER() asm volatile("s_waitcnt lgkmcnt(0)\n\ts_barrier" ::: "memory")

#define DPP_BCAST0 0x00
#define DPP_BCAST1 0x55
#define DPP_BCAST2 0xAA
#define DPP_BCAST3 0xFF
#define DPP_PAIR   0xF5
#define DPP_ROR4   0x124
#define DPP_ROR8   0x128
template<int CTRL>
__device__ __forceinline__ float dppf(float x) {
    int r = __builtin_amdgcn_update_dpp(0, __builtin_bit_cast(int, x), CTRL, 0xF, 0xF, true);
    return __builtin_bit_cast(float, r);
}

__device__ __forceinline__ h2 pk16(float a, float b) {
    return __builtin_bit_cast(h2, __builtin_amdgcn_cvt_pkrtz(a, b));
}

__device__ __forceinline__ void unpackh(h2 (&in)[24], const h2* __restrict__ row) {
    const float4* q = (const float4*)row;
#pragma unroll
    for (int k = 0; k < 6; ++k) {
        float4 v = q[k];
        in[4 * k + 0] = __builtin_bit_cast(h2, v.x);
        in[4 * k + 1] = __builtin_bit_cast(h2, v.y);
        in[4 * k + 2] = __builtin_bit_cast(h2, v.z);
        in[4 * k + 3] = __builtin_bit_cast(h2, v.w);
    }
}

__device__ __forceinline__ void loadx8c(float (&dst)[8], const float* __restrict__ xr,
                                        const float* __restrict__ xt,
                                        size_t xrb, size_t xtb, int k) {
#pragma unroll
    for (int m = 0; m < 8; ++m) {
        int v = 8 * k + m;
        dst[m] = (v < 47) ? xr[xrb + v] : ((v < 49) ? xt[xtb + (v - 47)] : 0.0f);
    }
}

// 3 waves. W0 = layer-0 via MFMA (lag 0). W1 = layer-1 via MFMA (lag 8).
// W2 = t-RNN DPP (lag 16) + x staging (8 ahead).
// v0 slot (96 f16 of 128): [h0(i-1) 0..46 | x48@47 | x(i) 48..95]
// v1 slot (96 f16 of 128): [h1(s-1) 0..46 | 0@47 | h0(s) 48..94 | 0@95]
//   NOTE: h1(s) is written to slot (s+1)&15, so h1(-1) must be pre-zeroed in SLOT 0
//   (R18's NaN: zeroed slot 15 by mistake).
// MFMA 16x16x32 f16: A lane layout m=l&15, k=(l>>4)*8+e; B col-replicated so
// B-frag = v[(l>>4)*8+e] (identical k-map as A -> any common k-map error cancels);
// D verified layout col=l&15, row=(l>>4)*4+reg (m89).
__global__ __launch_bounds__(192) void adrnn_fused(
    const float* __restrict__ x_r, const float* __restrict__ x_t,
    const float* __restrict__ rWih0, const float* __restrict__ rWhh0,
    const float* __restrict__ rbih0, const float* __restrict__ rbhh0,
    const float* __restrict__ rWih1, const float* __restrict__ rWhh1,
    const float* __restrict__ rbih1, const float* __restrict__ rbhh1,
    const float* __restrict__ tWih0, const float* __restrict__ tWhh0,
    const float* __restrict__ tbih0, const float* __restrict__ tbhh0,
    const float* __restrict__ tWih1, const float* __restrict__ tWhh1,
    const float* __restrict__ tbih1, const float* __restrict__ tbhh1,
    float* __restrict__ r_out, float* __restrict__ t_out)
{
    __shared__ __align__(16) h2 vring0[32][64];
    __shared__ __align__(16) h2 vring1[16][64];
    __shared__ __align__(16) h2 t1ring[16][24];   // h1(s) pairs for TT
    __shared__ __align__(16) float gbuf0[192];
    __shared__ __align__(16) float gbuf1[192];

    const int tid = threadIdx.x;
    const int wid = tid >> 6;
    const int l   = tid & 63;
    const int j   = l;
    const int b = blockIdx.x;
    const size_t xr_base = (size_t)b * T_STEPS * 47;
    const size_t xt_base = (size_t)b * T_STEPS * 2;

    // zero-inits (see ring layouts above)
    if (tid < 23) vring0[0][tid] = h2{(_Float16)0.0f, (_Float16)0.0f};
    else if (tid == 23) ((_Float16*)&vring0[0][0])[46] = (_Float16)0.0f;
    else if (tid >= 24 && tid < 48) vring1[0][tid - 24] = h2{(_Float16)0.0f, (_Float16)0.0f};
    else if (tid >= 48 && tid < 64) {
        int s = tid - 48;
        ((_Float16*)&vring1[s][0])[47] = (_Float16)0.0f;
        ((_Float16*)&vring1[s][0])[95] = (_Float16)0.0f;
        ((_Float16*)&t1ring[s][0])[47] = (_Float16)0.0f;
    }

    if (wid == 0) {
        // ===== W0: layer-0 MFMA. v0 cols: k<47 -> Whh0[:,k]; k==47 -> Wih0[:,48]; k>=48 -> Wih0[:,k-48]
        h8 A[12][3];
#pragma unroll
        for (int t = 0; t < 12; ++t) {
#pragma unroll
            for (int kk = 0; kk < 3; ++kk) {
                const int m = t * 16 + (l & 15);
#pragma unroll
                for (int e = 0; e < 8; ++e) {
                    const int k = kk * 32 + (l >> 4) * 8 + e;
                    float w = 0.0f;
                    if (m < 188) {
                        if (k < 47) w = rWhh0[m * 47 + k];
                        else if (k == 47) w = rWih0[m * 49 + 48];
                        else w = rWih0[m * 49 + (k - 48)];
                    }
                    A[t][kk][e] = (_Float16)w;
                }
            }
        }
        float b0 = 0, b1 = 0, b2 = 0, b3 = 0;
        if (j < 47) {
            b0 = rbih0[j] + rbhh0[j];
            b1 = rbih0[47 + j] + rbhh0[47 + j];
            b2 = rbih0[94 + j] + rbhh0[94 + j];
            b3 = rbih0[141 + j] + rbhh0[141 + j];
        }
        float c0 = 0.f;
        __syncthreads();
        for (int i = 0; i < TOTAL; ++i) {
            if (i < T_STEPS) {
                const float4* vrow = reinterpret_cast<const float4*>(&vring0[i & 31][0]);
                const int g4 = l >> 4;
                h8 bf0 = __builtin_bit_cast(h8, vrow[g4]);
                h8 bf1 = __builtin_bit_cast(h8, vrow[g4 + 4]);
                h8 bf2 = __builtin_bit_cast(h8, vrow[g4 + 8]);
#pragma unroll
                for (int t = 0; t < 12; ++t) {
                    f4v acc = {0.f, 0.f, 0.f, 0.f};
                    acc = __builtin_amdgcn_mfma_f32_16x16x32_f16(A[t][0], bf0, acc, 0, 0, 0);
                    acc = __builtin_amdgcn_mfma_f32_16x16x32_f16(A[t][1], bf1, acc, 0, 0, 0);
                    acc = __builtin_amdgcn_mfma_f32_16x16x32_f16(A[t][2], bf2, acc, 0, 0, 0);
                    if ((l & 15) == t) {
                        float4 st = {acc[0], acc[1], acc[2], acc[3]};
                        *reinterpret_cast<float4*>(&gbuf0[t * 16 + g4 * 4]) = st;
                    }
                }
                float hv = 0.f;
                if (j < 47) {
                    float p0 = gbuf0[j] + b0;
                    float p1 = gbuf0[47 + j] + b1;
                    float p2 = gbuf0[94 + j] + b2;
                    float p3 = gbuf0[141 + j] + b3;
                    float iv = sig_f(p0), fv = sig_f(p1);
                    float gv = tanh_f(p2), ov = sig_f(p3);
                    c0 = fmaf(fv, c0, iv * gv);
                    hv = ov * tanh_f(c0);
                }
                float hn = dppf<DPP_PAIR>(hv);
                if (j < 46 && !(j & 1)) {
                    h2 p = pk16(hv, hn);
                    vring0[(i + 1) & 31][j >> 1] = p;
                    vring1[i & 15][24 + (j >> 1)] = p;
                } else if (j == 46) {
                    ((_Float16*)&vring0[(i + 1) & 31][0])[46] = (_Float16)hv;
                    ((_Float16*)&vring1[i & 15][0])[94] = (_Float16)hv;
                }
            }
            if ((i & 7) == 7) LDS_BARRIER();
        }
    } else if (wid == 1) {
        // ===== W1: layer-1 MFMA (lag 8). v1 cols: k<47 -> Whh1[:,k]; 48<=k<95 -> Wih1[:,k-48]
        h8 A[12][3];
#pragma unroll
        for (int t = 0; t < 12; ++t) {
#pragma unroll
            for (int kk = 0; kk < 3; ++kk) {
                const int m = t * 16 + (l & 15);
#pragma unroll
                for (int e = 0; e < 8; ++e) {
                    const int k = kk * 32 + (l >> 4) * 8 + e;
                    float w = 0.0f;
                    if (m < 188) {
                        if (k < 47) w = rWhh1[m * 47 + k];
                        else if (k >= 48 && k < 95) w = rWih1[m * 47 + (k - 48)];
                    }
                    A[t][kk][e] = (_Float16)w;
                }
            }
        }
        float b0 = 0, b1 = 0, b2 = 0, b3 = 0;
        if (j < 47) {
            b0 = rbih1[j] + rbhh1[j];
            b1 = rbih1[47 + j] + rbhh1[47 + j];
            b2 = rbih1[94 + j] + rbhh1[94 + j];
            b3 = rbih1[141 + j] + rbhh1[141 + j];
        }
        float c1 = 0.f;
        __syncthreads();
        for (int i = 0; i < TOTAL; ++i) {
            const int s = i - 8;
            if (s >= 0 && s < T_STEPS) {
                const float4* vrow = reinterpret_cast<const float4*>(&vring1[s & 15][0]);
                const int g4 = l >> 4;
                h8 bf0 = __builtin_bit_cast(h8, vrow[g4]);
                h8 bf1 = __builtin_bit_cast(h8, vrow[g4 + 4]);
                h8 bf2 = __builtin_bit_cast(h8, vrow[g4 + 8]);
#pragma unroll
                for (int t = 0; t < 12; ++t) {
                    f4v acc = {0.f, 0.f, 0.f, 0.f};
                    acc = __builtin_amdgcn_mfma_f32_16x16x32_f16(A[t][0], bf0, acc, 0, 0, 0);
                    acc = __builtin_amdgcn_mfma_f32_16x16x32_f16(A[t][1], bf1, acc, 0, 0, 0);
                    acc = __builtin_amdgcn_mfma_f32_16x16x32_f16(A[t][2], bf2, acc, 0, 0, 0);
                    if ((l & 15) == t) {
                        float4 st = {acc[0], acc[1], acc[2], acc[3]};
                        *reinterpret_cast<float4*>(&gbuf1[t * 16 + g4 * 4]) = st;
                    }
                }
                float hv = 0.f;
                if (j < 47) {
                    float p0 = gbuf1[j] + b0;
                    float p1 = gbuf1[47 + j] + b1;
                    float p2 = gbuf1[94 + j] + b2;
                    float p3 = gbuf1[141 + j] + b3;
                    float iv = sig_f(p0), fv = sig_f(p1);
                    float gv = tanh_f(p2), ov = sig_f(p3);
                    c1 = fmaf(fv, c1, iv * gv);
                    hv = ov * tanh_f(c1);
                    r_out[((size_t)b * T_STEPS + s) * 47 + j] = hv;
                }
                float hn = dppf<DPP_PAIR>(hv);
                if (j < 46 && !(j & 1)) {
                    h2 p = pk16(hv, hn);
                    vring1[(s + 1) & 15][j >> 1] = p;
                    t1ring[s & 15][j >> 1] = p;
                } else if (j == 46) {
                    ((_Float16*)&vring1[(s + 1) & 15][0])[46] = (_Float16)hv;
                    ((_Float16*)&t1ring[s & 15][0])[46] = (_Float16)hv;
                }
            }
            if ((i & 7) == 7) LDS_BARRIER();
        }
    } else {
        // ===== W2: t-RNN (lag 16, DPP) + x staging (8 ahead, f16) =====
        const int tu  = (l >> 2) & 1;
        const int tg  = l & 3;
        const int thf = (l >> 3) & 1;
        const int R0 = tg * 2 + tu;
        h2 wt[24]; float wx48;
        if (thf == 0) {
            wx48 = 0.f;
#pragma unroll
            for (int u = 0; u < 24; ++u)
                wt[u] = h2{(_Float16)tWih0[R0 * 96 + 2 * u], (_Float16)tWih0[R0 * 96 + 2 * u + 1]};
        } else {
            wx48 = tWih0[R0 * 96 + 48];
#pragma unroll
            for (int u = 0; u < 23; ++u)
                wt[u] = h2{(_Float16)tWih0[R0 * 96 + 49 + 2 * u], (_Float16)tWih0[R0 * 96 + 49 + 2 * u + 1]};
            wt[23] = h2{(_Float16)tWih0[R0 * 96 + 95], (_Float16)0.0f};
        }
        const float bT0 = tbih0[R0] + tbhh0[R0];
        const float wh00 = tWhh0[R0 * 2 + 0], wh01 = tWhh0[R0 * 2 + 1];
        const float wi10 = tWih1[R0 * 2 + 0], wi11 = tWih1[R0 * 2 + 1];
        const float wh10 = tWhh1[R0 * 2 + 0], wh11 = tWhh1[R0 * 2 + 1];
        const float bT1 = tbih1[R0] + tbhh1[R0];
        const bool isg = (tg == 2);
        const float zm = isg ? 2.f : 1.f, sm = isg ? 2.f : 1.f, sa = isg ? -1.f : 0.f;
        float ht00 = 0.f, ht01 = 0.f, ct0u = 0.f;
        float ht10 = 0.f, ht11 = 0.f, ct1u = 0.f;

        float xa[8] = {0,0,0,0,0,0,0,0}, xb[8] = {0,0,0,0,0,0,0,0}, xc[8] = {0,0,0,0,0,0,0,0};
        if (l < 7) {
            for (int t = 0; t < 8; ++t) {
                float xv[8];
                loadx8c(xv, x_r, x_t, xr_base + (size_t)t * 47, xt_base + (size_t)t * 2, l);
                if (l < 6) {
                    h2* d = &vring0[t][24 + 4 * l];
                    d[0] = pk16(xv[0], xv[1]); d[1] = pk16(xv[2], xv[3]);
                    d[2] = pk16(xv[4], xv[5]); d[3] = pk16(xv[6], xv[7]);
                } else {
                    ((_Float16*)&vring0[t][0])[47] = (_Float16)xv[0];   // x48
                }
            }
            loadx8c(xa, x_r, x_t, xr_base + (size_t)8 * 47,  xt_base + (size_t)8 * 2,  l);
            loadx8c(xb, x_r, x_t, xr_base + (size_t)9 * 47,  xt_base + (size_t)9 * 2,  l);
            loadx8c(xc, x_r, x_t, xr_base + (size_t)10 * 47, xt_base + (size_t)10 * 2, l);
        }
        __syncthreads();

        for (int i = 0; i < TOTAL; ++i) {
            if (l < 7) {
                const int tw = i + 8;
                if (tw < T_STEPS) {
                    if (l < 6) {
                        h2* d = &vring0[tw & 31][24 + 4 * l];
                        d[0] = pk16(xa[0], xa[1]); d[1] = pk16(xa[2], xa[3]);
                        d[2] = pk16(xa[4], xa[5]); d[3] = pk16(xa[6], xa[7]);
                    } else {
                        ((_Float16*)&vring0[tw & 31][0])[47] = (_Float16)xa[0];
                    }
                }
#pragma unroll
                for (int m = 0; m < 8; ++m) { xa[m] = xb[m]; xb[m] = xc[m]; }
                int tl = i + 11;
                if (tl > T_STEPS - 1) tl = T_STEPS - 1;
                loadx8c(xc, x_r, x_t, xr_base + (size_t)tl * 47, xt_base + (size_t)tl * 2, l);
            }
            const int s = i - 16;
            if (s >= 0 && s < T_STEPS) {
                const h2* src = (thf == 0) ? &vring0[s & 31][24] : &t1ring[s & 15][0];
                h2 tin[24];
                unpackh(tin, src);
                float x48v = (float)((const _Float16*)&vring0[s & 31][0])[47];
                float acc = 0.f;
#pragma unroll
                for (int u = 0; u < 24; ++u) acc = FDOT2(wt[u], tin[u], acc);
                float part = (thf == 1) ? fmaf(wx48, x48v, acc) : acc;
                float pre0 = part + dppf<DPP_ROR8>(part);
                pre0 += bT0 + wh00 * ht00 + wh01 * ht01;
                float a0 = gate_act(pre0, zm, sm, sa);
                float i0 = dppf<DPP_BCAST0>(a0);
                float f0 = dppf<DPP_BCAST1>(a0);
                float g0v = dppf<DPP_BCAST2>(a0);
                float o0 = dppf<DPP_BCAST3>(a0);
                ct0u = fmaf(f0, ct0u, i0 * g0v);
                float htu = o0 * tanh_f(ct0u);
                float hto = dppf<DPP_ROR4>(htu);
                ht00 = (tu == 0) ? htu : hto;
                ht01 = (tu == 0) ? hto : htu;
                float pre1 = bT1 + wi10 * ht00 + wi11 * ht01 + wh10 * ht10 + wh11 * ht11;
                float a1 = gate_act(pre1, zm, sm, sa);
                float ji = dppf<DPP_BCAST0>(a1);
                float jf = dppf<DPP_BCAST1>(a1);
                float jg = dppf<DPP_BCAST2>(a1);
                float jo = dppf<DPP_BCAST3>(a1);
                ct1u = fmaf(jf, ct1u, ji * jg);
                float h1u = jo * tanh_f(ct1u);
                float h1o = dppf<DPP_ROR4>(h1u);
                ht10 = (tu == 0) ? h1u : h1o;
                ht11 = (tu == 0) ? h1o : h1u;
                if (l == 0) {
                    float2 tv = {ht10, ht11};
                    *reinterpret_cast<float2*>(&t_out[((size_t)b * T_STEPS + s) * 2]) = tv;
                }
            }
            if ((i & 7) == 7) LDS_BARRIER();
        }
    }
}

extern "C" void kernel_launch(void* const* d_in, const int* in_sizes, int n_in,
                              void* d_out, int out_size, void* d_ws, size_t ws_size,
                              hipStream_t stream) {
    const float* x_r   = (const float*)d_in[0];
    const float* x_t   = (const float*)d_in[1];
    const float* rWih0 = (const float*)d_in[2];
    const float* rWhh0 = (const float*)d_in[3];
    const float* rbih0 = (const float*)d_in[4];
    const float* rbhh0 = (const float*)d_in[5];
    const float* rWih1 = (const float*)d_in[6];
    const float* rWhh1 = (const float*)d_in[7];
    const float* rbih1 = (const float*)d_in[8];
    const float* rbhh1 = (const float*)d_in[9];
    const float* tWih0 = (const float*)d_in[10];
    const float* tWhh0 = (const float*)d_in[11];
    const float* tbih0 = (const float*)d_in[12];
    const float* tbhh0 = (const float*)d_in[13];
    const float* tWih1 = (const float*)d_in[14];
    const float* tWhh1 = (const float*)d_in[15];
    const float* tbih1 = (const float*)d_in[16];
    const float* tbhh1 = (const float*)d_in[17];

    float* r_out = (float*)d_out;
    float* t_out = r_out + (size_t)256 * T_STEPS * 47;

    hipLaunchKernelGGL(adrnn_fused, dim3(256), dim3(192), 0, stream,
                       x_r, x_t, rWih0, rWhh0, rbih0, rbhh0, rWih1, rWhh1, rbih1, rbhh1,
                       tWih0, tWhh0, tbih0, tbhh0, tWih1, tWhh1, tbih1, tbhh1,
                       r_out, t_out);
}

// Round 20
// 1263.082 us; speedup vs baseline: 1.4193x; 1.4193x over previous
//
#include <hip/hip_runtime.h>

#define T_STEPS 2048
#define TOTAL   2064   // T_STEPS + 16 (deepest lag: TT), multiple of 8

typedef float f2 __attribute__((ext_vector_type(2)));
typedef _Float16 h2 __attribute__((ext_vector_type(2)));

__device__ __forceinline__ float fast_rcp(float x) { return __builtin_amdgcn_rcpf(x); }
__device__ __forceinline__ float sig_f(float x) { return fast_rcp(1.0f + __expf(-x)); }
__device__ __forceinline__ float tanh_f(float x) {
    float e = __expf(-2.0f * x);
    return fmaf(2.0f, fast_rcp(1.0f + e), -1.0f);
}
__device__ __forceinline__ float gate_act(float x, float zm, float sm, float sa) {
    float e = __expf(-x * zm);
    return fmaf(fast_rcp(1.0f + e), sm, sa);
}

#if __has_builtin(__builtin_amdgcn_fdot2)
#define FDOT2(a, b, c) __builtin_amdgcn_fdot2((a), (b), (c), false)
#else
__device__ __forceinline__ float FDOT2(h2 a, h2 b, float c) {
    return fmaf((float)a.x, (float)b.x, fmaf((float)a.y, (float)b.y, c));
}
#endif

// Drain ONLY lgkmcnt (LDS) before barrier — never vmcnt (R7 win).
#define LDS_BARRIER() asm volatile("s_waitcnt lgkmcnt(0)\n\ts_barrier" ::: "memory")

#define DPP_BCAST0 0x00
#define DPP_BCAST1 0x55
#define DPP_BCAST2 0xAA
#define DPP_BCAST3 0xFF
#define DPP_PAIR   0xF5
#define DPP_ROR4   0x124
#define DPP_ROR8   0x128
template<int CTRL>
__device__ __forceinline__ float dppf(float x) {
    int r = __builtin_amdgcn_update_dpp(0, __builtin_bit_cast(int, x), CTRL, 0xF, 0xF, true);
    return __builtin_bit_cast(float, r);
}

__device__ __forceinline__ h2 pk16(float a, float b) {
    return __builtin_bit_cast(h2, __builtin_amdgcn_cvt_pkrtz(a, b));
}

__device__ __forceinline__ void unpackh(h2 (&in)[24], const h2* __restrict__ row) {
    const float4* q = (const float4*)row;
#pragma unroll
    for (int k = 0; k < 6; ++k) {
        float4 v = q[k];
        in[4 * k + 0] = __builtin_bit_cast(h2, v.x);
        in[4 * k + 1] = __builtin_bit_cast(h2, v.y);
        in[4 * k + 2] = __builtin_bit_cast(h2, v.z);
        in[4 * k + 3] = __builtin_bit_cast(h2, v.w);
    }
}
__device__ __forceinline__ void unpackx(h2 (&in)[28], const h2* __restrict__ row) {
    const float4* q = (const float4*)row;
#pragma unroll
    for (int k = 0; k < 7; ++k) {
        float4 v = q[k];
        in[4 * k + 0] = __builtin_bit_cast(h2, v.x);
        in[4 * k + 1] = __builtin_bit_cast(h2, v.y);
        in[4 * k + 2] = __builtin_bit_cast(h2, v.z);
        in[4 * k + 3] = __builtin_bit_cast(h2, v.w);
    }
}

__device__ __forceinline__ void loadw47h(h2 (&w)[24], const float* __restrict__ src) {
#pragma unroll
    for (int u = 0; u < 23; ++u)
        w[u] = h2{(_Float16)src[2 * u], (_Float16)src[2 * u + 1]};
    w[23] = h2{(_Float16)src[46], (_Float16)0.0f};
}
__device__ __forceinline__ void loadw49h(h2 (&w)[25], const float* __restrict__ src) {
#pragma unroll
    for (int u = 0; u < 24; ++u)
        w[u] = h2{(_Float16)src[2 * u], (_Float16)src[2 * u + 1]};
    w[24] = h2{(_Float16)src[48], (_Float16)0.0f};
}

__device__ __forceinline__ void loadx4c(float (&dst)[4], const float* __restrict__ x_r,
                                        const float* __restrict__ x_t,
                                        size_t xrb, size_t xtb, int k) {
#pragma unroll
    for (int m = 0; m < 4; ++m) {
        int v = 4 * k + m;
        dst[m] = (v < 47) ? x_r[xrb + v] : ((v < 49) ? x_t[xtb + (v - 47)] : 0.0f);
    }
}

// 3 waves: W0 = full layer-0 (lag 0), W1 = full layer-1 (lag 8), W2 = t-RNN (lag 16) + x staging.
// R20 = R17 structure (session best, 1271us) + s_setprio(1) around the recurrent waves'
// compute bodies (T5: pays when co-resident waves have role diversity; W2 is light).
__global__ __launch_bounds__(192) void adrnn_fused(
    const float* __restrict__ x_r, const float* __restrict__ x_t,
    const float* __restrict__ rWih0, const float* __restrict__ rWhh0,
    const float* __restrict__ rbih0, const float* __restrict__ rbhh0,
    const float* __restrict__ rWih1, const float* __restrict__ rWhh1,
    const float* __restrict__ rbih1, const float* __restrict__ rbhh1,
    const float* __restrict__ tWih0, const float* __restrict__ tWhh0,
    const float* __restrict__ tbih0, const float* __restrict__ tbhh0,
    const float* __restrict__ tWih1, const float* __restrict__ tWhh1,
    const float* __restrict__ tbih1, const float* __restrict__ tbhh1,
    float* __restrict__ r_out, float* __restrict__ t_out)
{
    __shared__ __align__(16) h2 xring[32][28];
    __shared__ __align__(16) h2 h0f16[16][24];
    __shared__ __align__(16) h2 h1f16[16][24];

    const int tid = threadIdx.x;
    const int wid = tid >> 6;
    const int l   = tid & 63;
    const int j   = l;
    const int b = blockIdx.x;
    const size_t xr_base = (size_t)b * T_STEPS * 47;
    const size_t xt_base = (size_t)b * T_STEPS * 2;

    for (int k = tid; k < 16 * 24; k += 192) {
        h0f16[k / 24][k % 24] = h2{(_Float16)0.0f, (_Float16)0.0f};
        h1f16[k / 24][k % 24] = h2{(_Float16)0.0f, (_Float16)0.0f};
    }

    if (wid == 0) {
        // ===== W0: layer-0 =====
        h2 wx[4][25]; h2 wh[4][24]; float bias[4] = {0, 0, 0, 0};
#pragma unroll
        for (int g = 0; g < 4; ++g) {
#pragma unroll
            for (int u = 0; u < 25; ++u) wx[g][u] = h2{(_Float16)0.0f, (_Float16)0.0f};
#pragma unroll
            for (int u = 0; u < 24; ++u) wh[g][u] = h2{(_Float16)0.0f, (_Float16)0.0f};
        }
        if (j < 47) {
#pragma unroll
            for (int g = 0; g < 4; ++g) {
                const int row = g * 47 + j;
                loadw49h(wx[g], &rWih0[row * 49]);
                loadw47h(wh[g], &rWhh0[row * 47]);
                bias[g] = rbih0[row] + rbhh0[row];
            }
        }
        float c0 = 0.f;
        __syncthreads();
        for (int g0 = 0; g0 < TOTAL; g0 += 8) {
            __builtin_amdgcn_s_setprio(1);
#pragma unroll
            for (int k8 = 0; k8 < 8; ++k8) {
                const int i = g0 + k8;
                float hv = 0.0f;
                if (i < T_STEPS && j < 47) {
                    h2 xin[28];
                    unpackx(xin, &xring[i & 31][0]);
                    h2 hin[24];
                    unpackh(hin, &h0f16[(i - 1) & 15][0]);
                    float a0 = bias[0], a1 = bias[1], a2 = bias[2], a3 = bias[3];
#pragma unroll
                    for (int u = 0; u < 25; ++u) {
                        a0 = FDOT2(wx[0][u], xin[u], a0);
                        a1 = FDOT2(wx[1][u], xin[u], a1);
                        a2 = FDOT2(wx[2][u], xin[u], a2);
                        a3 = FDOT2(wx[3][u], xin[u], a3);
                    }
#pragma unroll
                    for (int u = 0; u < 24; ++u) {
                        a0 = FDOT2(wh[0][u], hin[u], a0);
                        a1 = FDOT2(wh[1][u], hin[u], a1);
                        a2 = FDOT2(wh[2][u], hin[u], a2);
                        a3 = FDOT2(wh[3][u], hin[u], a3);
                    }
                    float iv = sig_f(a0), fv = sig_f(a1);
                    float gv = tanh_f(a2), ov = sig_f(a3);
                    c0 = fmaf(fv, c0, iv * gv);
                    hv = ov * tanh_f(c0);
                }
                float hn = dppf<DPP_PAIR>(hv);
                if (i < T_STEPS && j < 47 && !(j & 1)) h0f16[i & 15][j >> 1] = pk16(hv, hn);
            }
            __builtin_amdgcn_s_setprio(0);
            LDS_BARRIER();
        }
    } else if (wid == 1) {
        // ===== W1: layer-1 (lag 8) =====
        h2 wx[4][24]; h2 wh[4][24]; float bias[4] = {0, 0, 0, 0};
#pragma unroll
        for (int g = 0; g < 4; ++g) {
#pragma unroll
            for (int u = 0; u < 24; ++u) {
                wx[g][u] = h2{(_Float16)0.0f, (_Float16)0.0f};
                wh[g][u] = h2{(_Float16)0.0f, (_Float16)0.0f};
            }
        }
        if (j < 47) {
#pragma unroll
            for (int g = 0; g < 4; ++g) {
                const int row = g * 47 + j;
                loadw47h(wx[g], &rWih1[row * 47]);
                loadw47h(wh[g], &rWhh1[row * 47]);
                bias[g] = rbih1[row] + rbhh1[row];
            }
        }
        float c1 = 0.f;
        __syncthreads();
        for (int g0 = 0; g0 < TOTAL; g0 += 8) {
            __builtin_amdgcn_s_setprio(1);
#pragma unroll
            for (int k8 = 0; k8 < 8; ++k8) {
                const int i = g0 + k8;
                const int s = i - 8;
                float hv = 0.0f;
                if (s >= 0 && s < T_STEPS && j < 47) {
                    h2 xin[24];
                    unpackh(xin, &h0f16[s & 15][0]);
                    h2 hin[24];
                    unpackh(hin, &h1f16[(s - 1) & 15][0]);
                    float a0 = bias[0], a1 = bias[1], a2 = bias[2], a3 = bias[3];
#pragma unroll
                    for (int u = 0; u < 24; ++u) {
                        a0 = FDOT2(wx[0][u], xin[u], a0);
                        a1 = FDOT2(wx[1][u], xin[u], a1);
                        a2 = FDOT2(wx[2][u], xin[u], a2);
                        a3 = FDOT2(wx[3][u], xin[u], a3);
                    }
#pragma unroll
                    for (int u = 0; u < 24; ++u) {
                        a0 = FDOT2(wh[0][u], hin[u], a0);
                        a1 = FDOT2(wh[1][u], hin[u], a1);
                        a2 = FDOT2(wh[2][u], hin[u], a2);
                        a3 = FDOT2(wh[3][u], hin[u], a3);
                    }
                    float iv = sig_f(a0), fv = sig_f(a1);
                    float gv = tanh_f(a2), ov = sig_f(a3);
                    c1 = fmaf(fv, c1, iv * gv);
                    hv = ov * tanh_f(c1);
                    r_out[((size_t)b * T_STEPS + s) * 47 + j] = hv;
                }
                float hn = dppf<DPP_PAIR>(hv);
                if (s >= 0 && s < T_STEPS && j < 47 && !(j & 1)) h1f16[s & 15][j >> 1] = pk16(hv, hn);
            }
            __builtin_amdgcn_s_setprio(0);
            LDS_BARRIER();
        }
    } else {
        // ===== W2: t-RNN (lag 16) + x staging (8 ahead, f16) =====
        const int tu  = (l >> 2) & 1;
        const int tg  = l & 3;
        const int thf = (l >> 3) & 1;
        const int R0 = tg * 2 + tu;
        h2 wt[24]; float wx48;
        if (thf == 0) {
            wx48 = 0.f;
#pragma unroll
            for (int u = 0; u < 24; ++u)
                wt[u] = h2{(_Float16)tWih0[R0 * 96 + 2 * u], (_Float16)tWih0[R0 * 96 + 2 * u + 1]};
        } else {
            wx48 = tWih0[R0 * 96 + 48];
#pragma unroll
            for (int u = 0; u < 23; ++u)
                wt[u] = h2{(_Float16)tWih0[R0 * 96 + 49 + 2 * u], (_Float16)tWih0[R0 * 96 + 49 + 2 * u + 1]};
            wt[23] = h2{(_Float16)tWih0[R0 * 96 + 95], (_Float16)0.0f};
        }
        const float bT0 = tbih0[R0] + tbhh0[R0];
        const float wh00 = tWhh0[R0 * 2 + 0], wh01 = tWhh0[R0 * 2 + 1];
        const float wi10 = tWih1[R0 * 2 + 0], wi11 = tWih1[R0 * 2 + 1];
        const float wh10 = tWhh1[R0 * 2 + 0], wh11 = tWhh1[R0 * 2 + 1];
        const float bT1 = tbih1[R0] + tbhh1[R0];
        const bool isg = (tg == 2);
        const float zm = isg ? 2.f : 1.f, sm = isg ? 2.f : 1.f, sa = isg ? -1.f : 0.f;
        float ht00 = 0.f, ht01 = 0.f, ct0u = 0.f;
        float ht10 = 0.f, ht11 = 0.f, ct1u = 0.f;

        float xa[4] = {0,0,0,0}, xb[4] = {0,0,0,0}, xc[4] = {0,0,0,0};
        if (l < 13) {
            for (int t = 0; t < 8; ++t) {
                float xv[4];
                loadx4c(xv, x_r, x_t, xr_base + (size_t)t * 47, xt_base + (size_t)t * 2, l);
                xring[t][2 * l]     = pk16(xv[0], xv[1]);
                xring[t][2 * l + 1] = pk16(xv[2], xv[3]);
            }
            loadx4c(xa, x_r, x_t, xr_base + (size_t)8 * 47,  xt_base + (size_t)8 * 2,  l);
            loadx4c(xb, x_r, x_t, xr_base + (size_t)9 * 47,  xt_base + (size_t)9 * 2,  l);
            loadx4c(xc, x_r, x_t, xr_base + (size_t)10 * 47, xt_base + (size_t)10 * 2, l);
        }
        __syncthreads();

        for (int g0 = 0; g0 < TOTAL; g0 += 8) {
#pragma unroll
            for (int k8 = 0; k8 < 8; ++k8) {
                const int i = g0 + k8;
                if (l < 13) {
                    const int tw = i + 8;
                    if (tw < T_STEPS) {
                        xring[tw & 31][2 * l]     = pk16(xa[0], xa[1]);
                        xring[tw & 31][2 * l + 1] = pk16(xa[2], xa[3]);
                    }
#pragma unroll
                    for (int m = 0; m < 4; ++m) { xa[m] = xb[m]; xb[m] = xc[m]; }
                    int tl = i + 11;
                    if (tl > T_STEPS - 1) tl = T_STEPS - 1;
                    loadx4c(xc, x_r, x_t, xr_base + (size_t)tl * 47, xt_base + (size_t)tl * 2, l);
                }
                const int s = i - 16;
                if (s >= 0 && s < T_STEPS) {
                    const h2* src = (thf == 0) ? &xring[s & 31][0] : &h1f16[s & 15][0];
                    h2 tin[24];
                    unpackh(tin, src);
                    float x48v = (float)xring[s & 31][24].x;
                    float acc = 0.f;
#pragma unroll
                    for (int u = 0; u < 24; ++u) acc = FDOT2(wt[u], tin[u], acc);
                    float part = (thf == 1) ? fmaf(wx48, x48v, acc) : acc;
                    float pre0 = part + dppf<DPP_ROR8>(part);
                    pre0 += bT0 + wh00 * ht00 + wh01 * ht01;
                    float a0 = gate_act(pre0, zm, sm, sa);
                    float i0 = dppf<DPP_BCAST0>(a0);
                    float f0 = dppf<DPP_BCAST1>(a0);
                    float g0v = dppf<DPP_BCAST2>(a0);
                    float o0 = dppf<DPP_BCAST3>(a0);
                    ct0u = fmaf(f0, ct0u, i0 * g0v);
                    float htu = o0 * tanh_f(ct0u);
                    float hto = dppf<DPP_ROR4>(htu);
                    ht00 = (tu == 0) ? htu : hto;
                    ht01 = (tu == 0) ? hto : htu;
                    float pre1 = bT1 + wi10 * ht00 + wi11 * ht01 + wh10 * ht10 + wh11 * ht11;
                    float a1 = gate_act(pre1, zm, sm, sa);
                    float ji = dppf<DPP_BCAST0>(a1);
                    float jf = dppf<DPP_BCAST1>(a1);
                    float jg = dppf<DPP_BCAST2>(a1);
                    float jo = dppf<DPP_BCAST3>(a1);
                    ct1u = fmaf(jf, ct1u, ji * jg);
                    float h1u = jo * tanh_f(ct1u);
                    float h1o = dppf<DPP_ROR4>(h1u);
                    ht10 = (tu == 0) ? h1u : h1o;
                    ht11 = (tu == 0) ? h1o : h1u;
                    if (l == 0) {
                        float2 tv = {ht10, ht11};
                        *reinterpret_cast<float2*>(&t_out[((size_t)b * T_STEPS + s) * 2]) = tv;
                    }
                }
            }
            LDS_BARRIER();
        }
    }
}

extern "C" void kernel_launch(void* const* d_in, const int* in_sizes, int n_in,
                              void* d_out, int out_size, void* d_ws, size_t ws_size,
                              hipStream_t stream) {
    const float* x_r   = (const float*)d_in[0];
    const float* x_t   = (const float*)d_in[1];
    const float* rWih0 = (const float*)d_in[2];
    const float* rWhh0 = (const float*)d_in[3];
    const float* rbih0 = (const float*)d_in[4];
    const float* rbhh0 = (const float*)d_in[5];
    const float* rWih1 = (const float*)d_in[6];
    const float* rWhh1 = (const float*)d_in[7];
    const float* rbih1 = (const float*)d_in[8];
    const float* rbhh1 = (const float*)d_in[9];
    const float* tWih0 = (const float*)d_in[10];
    const float* tWhh0 = (const float*)d_in[11];
    const float* tbih0 = (const float*)d_in[12];
    const float* tbhh0 = (const float*)d_in[13];
    const float* tWih1 = (const float*)d_in[14];
    const float* tWhh1 = (const float*)d_in[15];
    const float* tbih1 = (const float*)d_in[16];
    const float* tbhh1 = (const float*)d_in[17];

    float* r_out = (float*)d_out;
    float* t_out = r_out + (size_t)256 * T_STEPS * 47;

    hipLaunchKernelGGL(adrnn_fused, dim3(256), dim3(192), 0, stream,
                       x_r, x_t, rWih0, rWhh0, rbih0, rbhh0, rWih1, rWhh1, rbih1, rbhh1,
                       tWih0, tWhh0, tbih0, tbhh0, tWih1, tWhh1, tbih1, tbhh1,
                       r_out, t_out);
}